// Round 1
// baseline (164.018 us; speedup 1.0000x reference)
//
#include <hip/hip_runtime.h>
#include <hip/hip_bf16.h>
#include <cstdint>

#define V_N    50000
#define C_N    128
#define COUT_N 256
#define DEG_N  16
#define K2_N   256   // 2*C

typedef short bf16x8 __attribute__((ext_vector_type(8)));
typedef float f32x4  __attribute__((ext_vector_type(4)));

__device__ __forceinline__ unsigned short f2bf(float f) {
    union { float f; unsigned u; } a; a.f = f;
    unsigned r = a.u + 0x7fffu + ((a.u >> 16) & 1u);   // round-to-nearest-even
    return (unsigned short)(r >> 16);
}

// Transpose + convert kernel weights: Bt[n][k] = bf16(kernel[k][n]).
// 128KB output into d_ws. Tiny one-shot cost.
__global__ void prep_bt_kernel(const float* __restrict__ kern,
                               unsigned short* __restrict__ bt) {
    const int k = blockIdx.x;    // 0..255 (2C rows)
    const int n = threadIdx.x;   // 0..255 (COUT cols)
    bt[n * K2_N + k] = f2bf(kern[k * COUT_N + n]);
}

// Fused: per-vertex weighted aggregation -> bf16 A tile in LDS -> MFMA GEMM.
// Block = 512 threads (8 waves), BM = 128 vertices, full N=256 in two halves.
// LDS: A tile [128][256] bf16 (64KB, XOR-swizzled) + Bt half [128][256] bf16 (64KB, XOR-swizzled).
__global__ __launch_bounds__(512)
void dgc_fused_kernel(const float* __restrict__ data,
                      const int* __restrict__ edge_dst,
                      const float* __restrict__ edge_w,
                      const unsigned short* __restrict__ btg,
                      const float* __restrict__ bias,
                      float* __restrict__ out) {
    extern __shared__ __align__(16) char smem[];
    char* Asm = smem;             // 65536 B
    char* Bsm = smem + 65536;     // 65536 B

    const int tid  = threadIdx.x;
    const int lane = tid & 63;
    const int wid  = __builtin_amdgcn_readfirstlane(tid >> 6);  // wave id, provably uniform
    const int m0   = blockIdx.x * 128;

    // ---------------- Phase 1: aggregate 128 vertices -> A tile (bf16, swizzled) ---------
    // wave handles 16 vertices; lane covers channels {2*lane, 2*lane+1} (float2, 512B/row coalesced)
    #pragma unroll 2
    for (int t = 0; t < 16; ++t) {
        const int row = wid * 16 + t;
        const int vtx = m0 + row;
        float sx = 0.f, sy = 0.f, Wsum = 0.f;
        float ux = 0.f, uy = 0.f, vx = 0.f, vy = 0.f;
        if (vtx < V_N) {
            const int*   __restrict__ dst = edge_dst + vtx * DEG_N;
            const float* __restrict__ ww  = edge_w  + vtx * DEG_N;
            #pragma unroll
            for (int k = 0; k < DEG_N; ++k) {
                const float wk = ww[k];                 // wave-uniform -> s_load
                const int   j  = dst[k];                // wave-uniform -> s_load
                const float2 y = *reinterpret_cast<const float2*>(
                    data + (size_t)j * C_N + lane * 2);
                sx = fmaf(wk, y.x, sx);
                sy = fmaf(wk, y.y, sy);
                Wsum += wk;
            }
            const float2 x = *reinterpret_cast<const float2*>(
                data + (size_t)vtx * C_N + lane * 2);
            ux = Wsum * x.x;  uy = Wsum * x.y;
            vx = sx - ux;     vy = sy - uy;
        }
        // A row layout: k<128 -> u = W*x ; k>=128 -> v = s - W*x  (512B row, 32 x 16B chunks)
        // swizzle: chunk ^= (row & 7)  -> conflict-free ds_read_b128 in phase 2
        const unsigned up = (unsigned)f2bf(ux) | ((unsigned)f2bf(uy) << 16);
        const unsigned vp = (unsigned)f2bf(vx) | ((unsigned)f2bf(vy) << 16);
        const int sw     = row & 7;
        const int cu     = lane >> 2;          // chunk of the u pair
        const int within = (lane & 3) * 4;
        char* rowp = Asm + row * 512;
        *reinterpret_cast<unsigned*>(rowp + ((cu        ^ sw) * 16 + within)) = up;
        *reinterpret_cast<unsigned*>(rowp + (((16 + cu) ^ sw) * 16 + within)) = vp;
    }
    __syncthreads();

    // ---------------- Phase 2: A[128x256] @ K[256x256] via MFMA, two 128-col halves ------
    const int wm = wid >> 1;   // 0..3 : 32-row wave tile
    const int wn = wid & 1;    // 0..1 : 64-col wave tile

    for (int h = 0; h < 2; ++h) {
        if (h == 1) __syncthreads();    // drain reads of Bsm before overwrite
        // Load Bt half [n=h*128..+128)[k=0..256) bf16 into LDS with same XOR swizzle.
        // LDS chunk (n,c) holds global Bt chunk (n, c ^ (n&7)).
        #pragma unroll
        for (int rep = 0; rep < 8; ++rep) {
            const int q = rep * 512 + tid;          // 0..4095 16B chunks
            const int n = q >> 5;
            const int c = q & 31;
            const uint4 val = *reinterpret_cast<const uint4*>(
                btg + (size_t)(h * 128 + n) * K2_N + (size_t)(c ^ (n & 7)) * 8);
            *reinterpret_cast<uint4*>(Bsm + q * 16) = val;
        }
        __syncthreads();

        f32x4 acc[2][4];
        #pragma unroll
        for (int mf = 0; mf < 2; ++mf)
            #pragma unroll
            for (int nf = 0; nf < 4; ++nf)
                acc[mf][nf] = (f32x4){0.f, 0.f, 0.f, 0.f};

        #pragma unroll
        for (int ks = 0; ks < 8; ++ks) {   // K = 256 = 8 * 32
            bf16x8 a[2], b[4];
            #pragma unroll
            for (int mf = 0; mf < 2; ++mf) {
                const int r  = wm * 32 + mf * 16 + (lane & 15);
                const int ck = (ks * 4 + (lane >> 4)) ^ (r & 7);
                a[mf] = *reinterpret_cast<const bf16x8*>(Asm + r * 512 + ck * 16);
            }
            #pragma unroll
            for (int nf = 0; nf < 4; ++nf) {
                const int n  = wn * 64 + nf * 16 + (lane & 15);
                const int ck = (ks * 4 + (lane >> 4)) ^ (n & 7);
                b[nf] = *reinterpret_cast<const bf16x8*>(Bsm + n * 512 + ck * 16);
            }
            #pragma unroll
            for (int mf = 0; mf < 2; ++mf)
                #pragma unroll
                for (int nf = 0; nf < 4; ++nf)
                    acc[mf][nf] = __builtin_amdgcn_mfma_f32_16x16x32_bf16(
                        a[mf], b[nf], acc[mf][nf], 0, 0, 0);
        }

        // Epilogue: C/D layout col = lane&15, row = (lane>>4)*4 + reg. out += bias (Σw==1).
        #pragma unroll
        for (int mf = 0; mf < 2; ++mf) {
            const int row_l = wm * 32 + mf * 16 + (lane >> 4) * 4;
            #pragma unroll
            for (int nf = 0; nf < 4; ++nf) {
                const int col = h * 128 + wn * 64 + nf * 16 + (lane & 15);
                const float bb = bias[col];
                #pragma unroll
                for (int r = 0; r < 4; ++r) {
                    const int rg = m0 + row_l + r;
                    if (rg < V_N)
                        out[(size_t)rg * COUT_N + col] = acc[mf][nf][r] + bb;
                }
            }
        }
    }
}

extern "C" void kernel_launch(void* const* d_in, const int* in_sizes, int n_in,
                              void* d_out, int out_size, void* d_ws, size_t ws_size,
                              hipStream_t stream) {
    const float* data     = (const float*)d_in[0];
    // d_in[1] = edge_src: implicit (vertex i owns edges [16i,16i+16)), unused
    const int*   edge_dst = (const int*)d_in[2];
    const float* edge_w   = (const float*)d_in[3];
    const float* kern     = (const float*)d_in[4];
    const float* bias     = (const float*)d_in[5];
    float*       out      = (float*)d_out;

    unsigned short* bt = (unsigned short*)d_ws;   // 256*256*2 = 128KB

    prep_bt_kernel<<<K2_N, COUT_N, 0, stream>>>(kern, bt);

    // 128KB dynamic LDS: opt-in (idempotent; safe under graph capture)
    static const int kLds = 131072;
    hipFuncSetAttribute(reinterpret_cast<const void*>(dgc_fused_kernel),
                        hipFuncAttributeMaxDynamicSharedMemorySize, kLds);

    const int nblk = (V_N + 127) / 128;   // 391
    dgc_fused_kernel<<<nblk, 512, kLds, stream>>>(data, edge_dst, edge_w, bt, bias, out);
}

// Round 2
// 150.338 us; speedup vs baseline: 1.0910x; 1.0910x over previous
//
#include <hip/hip_runtime.h>
#include <hip/hip_bf16.h>
#include <cstdint>

#define V_N    50000
#define C_N    128
#define COUT_N 256
#define DEG_N  16
#define K2_N   256   // 2*C

typedef short bf16x8 __attribute__((ext_vector_type(8)));
typedef float f32x4  __attribute__((ext_vector_type(4)));

__device__ __forceinline__ unsigned short f2bf(float f) {
    union { float f; unsigned u; } a; a.f = f;
    unsigned r = a.u + 0x7fffu + ((a.u >> 16) & 1u);   // round-to-nearest-even
    return (unsigned short)(r >> 16);
}
__device__ __forceinline__ float bf2f(unsigned h) {
    union { unsigned u; float f; } a; a.u = h << 16; return a.f;
}

// Transpose + convert kernel weights: Bt[n][k] = bf16(kernel[k][n]).  128KB in d_ws.
__global__ void prep_bt_kernel(const float* __restrict__ kern,
                               unsigned short* __restrict__ bt) {
    const int k = blockIdx.x;    // 0..255 (2C rows)
    const int n = threadIdx.x;   // 0..255 (COUT cols)
    bt[n * K2_N + k] = f2bf(kern[k * COUT_N + n]);
}

// Convert data fp32 -> bf16 table (halves gather bytes). 12.8MB in d_ws.
__global__ __launch_bounds__(256)
void prep_data_kernel(const float* __restrict__ data,
                      unsigned short* __restrict__ db) {
    const int i = blockIdx.x * 256 + threadIdx.x;        // unit of 8 floats; grid exact
    const float4 f0 = *reinterpret_cast<const float4*>(data + (size_t)i * 8);
    const float4 f1 = *reinterpret_cast<const float4*>(data + (size_t)i * 8 + 4);
    union { unsigned short h[8]; uint4 q; } o;
    o.h[0] = f2bf(f0.x); o.h[1] = f2bf(f0.y); o.h[2] = f2bf(f0.z); o.h[3] = f2bf(f0.w);
    o.h[4] = f2bf(f1.x); o.h[5] = f2bf(f1.y); o.h[6] = f2bf(f1.z); o.h[7] = f2bf(f1.w);
    *reinterpret_cast<uint4*>(db + (size_t)i * 8) = o.q;
}

// Fused: weighted aggregation (bf16 gathers, fp32 accum) -> A tile in LDS -> MFMA.
// Block = 256 threads (4 waves), BM = 64 vertices. LDS = A tile only: 64x512B = 32KB,
// XOR-swizzled (chunk ^= row&7) for conflict-free ds_read_b128.
// B fragments come straight from global Bt (128KB, L2-resident).
__global__ __launch_bounds__(256, 4)
void dgc_fused_kernel(const unsigned short* __restrict__ db,
                      const int* __restrict__ edge_dst,
                      const float* __restrict__ edge_w,
                      const unsigned short* __restrict__ btg,
                      const float* __restrict__ bias,
                      float* __restrict__ out) {
    __shared__ __align__(16) char Asm[64 * 512];

    const int tid  = threadIdx.x;
    const int lane = tid & 63;
    const int wid  = __builtin_amdgcn_readfirstlane(tid >> 6);
    const int m0   = blockIdx.x * 64;

    // ---------- Phase 1: aggregate 64 vertices (16 per wave) ----------
    // lane covers channels {2*lane, 2*lane+1}; one row = 256B, fully coalesced.
    #pragma unroll 2
    for (int t = 0; t < 16; ++t) {
        const int row = wid * 16 + t;
        const int vtx = m0 + row;
        float ux = 0.f, uy = 0.f, vx = 0.f, vy = 0.f;
        if (vtx < V_N) {
            const int*   __restrict__ dst = edge_dst + vtx * DEG_N;
            const float* __restrict__ ww  = edge_w  + vtx * DEG_N;
            float sx = 0.f, sy = 0.f, Wsum = 0.f;
            #pragma unroll
            for (int k = 0; k < DEG_N; ++k) {
                const float wk = ww[k];                     // wave-uniform
                const int   j  = dst[k];                    // wave-uniform
                const unsigned p = *reinterpret_cast<const unsigned*>(
                    db + (size_t)j * C_N + lane * 2);
                sx = fmaf(wk, bf2f(p & 0xffffu), sx);
                sy = fmaf(wk, bf2f(p >> 16), sy);
                Wsum += wk;
            }
            const unsigned xp = *reinterpret_cast<const unsigned*>(
                db + (size_t)vtx * C_N + lane * 2);
            ux = Wsum * bf2f(xp & 0xffffu);
            uy = Wsum * bf2f(xp >> 16);
            vx = sx - ux;
            vy = sy - uy;
        }
        // A row: k<128 -> u = W*x ; k>=128 -> v = s - W*x. 32 x 16B chunks, chunk ^= row&7.
        const unsigned up = (unsigned)f2bf(ux) | ((unsigned)f2bf(uy) << 16);
        const unsigned vp = (unsigned)f2bf(vx) | ((unsigned)f2bf(vy) << 16);
        const int sw     = row & 7;
        const int cu     = lane >> 2;
        const int within = (lane & 3) * 4;
        char* rowp = Asm + row * 512;
        *reinterpret_cast<unsigned*>(rowp + ((cu        ^ sw) * 16 + within)) = up;
        *reinterpret_cast<unsigned*>(rowp + (((16 + cu) ^ sw) * 16 + within)) = vp;
    }
    __syncthreads();

    // ---------- Phase 2: A[64x256] @ K[256x256], B from global ----------
    const int wm = wid >> 1;   // 0..1 : 32-row wave tile
    const int wn = wid & 1;    // 0..1 : 64-col wave tile (within 128-col half)

    #pragma unroll
    for (int h = 0; h < 2; ++h) {
        f32x4 acc[2][4];
        #pragma unroll
        for (int mf = 0; mf < 2; ++mf)
            #pragma unroll
            for (int nf = 0; nf < 4; ++nf)
                acc[mf][nf] = (f32x4){0.f, 0.f, 0.f, 0.f};

        #pragma unroll
        for (int ks = 0; ks < 8; ++ks) {     // K = 256 = 8 * 32
            bf16x8 a[2], b[4];
            #pragma unroll
            for (int mf = 0; mf < 2; ++mf) {
                const int r  = wm * 32 + mf * 16 + (lane & 15);
                const int ck = (ks * 4 + (lane >> 4)) ^ (r & 7);
                a[mf] = *reinterpret_cast<const bf16x8*>(Asm + r * 512 + ck * 16);
            }
            #pragma unroll
            for (int nf = 0; nf < 4; ++nf) {
                const int n = h * 128 + wn * 64 + nf * 16 + (lane & 15);
                b[nf] = *reinterpret_cast<const bf16x8*>(
                    btg + (size_t)n * K2_N + (ks * 4 + (lane >> 4)) * 8);
            }
            #pragma unroll
            for (int mf = 0; mf < 2; ++mf)
                #pragma unroll
                for (int nf = 0; nf < 4; ++nf)
                    acc[mf][nf] = __builtin_amdgcn_mfma_f32_16x16x32_bf16(
                        a[mf], b[nf], acc[mf][nf], 0, 0, 0);
        }

        // Epilogue: C/D layout col = lane&15, row = (lane>>4)*4 + reg. bias ok (Σw==1).
        #pragma unroll
        for (int mf = 0; mf < 2; ++mf) {
            const int row_l = wm * 32 + mf * 16 + (lane >> 4) * 4;
            #pragma unroll
            for (int nf = 0; nf < 4; ++nf) {
                const int col = h * 128 + wn * 64 + nf * 16 + (lane & 15);
                const float bb = bias[col];
                #pragma unroll
                for (int r = 0; r < 4; ++r) {
                    const int rg = m0 + row_l + r;
                    if (rg < V_N)
                        out[(size_t)rg * COUT_N + col] = acc[mf][nf][r] + bb;
                }
            }
        }
    }
}

extern "C" void kernel_launch(void* const* d_in, const int* in_sizes, int n_in,
                              void* d_out, int out_size, void* d_ws, size_t ws_size,
                              hipStream_t stream) {
    const float* data     = (const float*)d_in[0];
    // d_in[1] = edge_src: implicit (vertex i owns edges [16i,16i+16)), unused
    const int*   edge_dst = (const int*)d_in[2];
    const float* edge_w   = (const float*)d_in[3];
    const float* kern     = (const float*)d_in[4];
    const float* bias     = (const float*)d_in[5];
    float*       out      = (float*)d_out;

    unsigned short* bt = (unsigned short*)d_ws;                  // 128KB
    unsigned short* db = (unsigned short*)d_ws + (size_t)K2_N * COUT_N;  // 12.8MB bf16 data

    prep_bt_kernel<<<K2_N, COUT_N, 0, stream>>>(kern, bt);
    prep_data_kernel<<<(V_N * C_N / 8) / 256, 256, 0, stream>>>(data, db);

    const int nblk = (V_N + 63) / 64;   // 782
    dgc_fused_kernel<<<nblk, 256, 0, stream>>>(db, edge_dst, edge_w, bt, bias, out);
}